// Round 6
// baseline (6623.451 us; speedup 1.0000x reference)
//
#include <hip/hip_runtime.h>
#include <stdint.h>

// Teacher-forced LSTM, B=64 T=512 D=H=1024.
// a(t) = m(t)*h(t-1) + (1-m(t))*x(t)  (computed in previous step's cell phase)
// gates(t) = [a(t) | h(t-1)] @ [Wx | Wh]^T + bias   -- one K=2048 GEMM
// Persistent: 128 blocks x 512 thr; block owns 8 hidden units (32 gate rows).
// Weights bf16 LDS-stationary. 32x32x16 MFMA; 8 waves = 2 Mtiles x 4 Kquarters.
// A-panel exchanged via ws: producers use agent-scope write-through stores;
// consumers use batched inline-asm global_load_dwordx4 sc0 (L1-bypass,
// L2-CACHED -> 16 blocks/XCD share one L3 fill). Per-step, one leader block
// per real XCD (HW_REG_XCC_ID) invalidates its L2 (acquire-agent fence;
// nothing is ever dirty: ALL global stores are agent write-through) between
// the global arrive-barrier and ready[xcd] release. No writebacks anywhere.

#define B_ 64
#define T_ 512
#define D_ 1024
#define H_ 1024
#define NBLK 128
#define UPB 8
#define NROW 32
#define NTHR 512

typedef __attribute__((ext_vector_type(8))) short short8;
typedef __attribute__((ext_vector_type(16))) float f32x16;

// LDS (bytes): W 32x4096 swizzled @0 | gbuf float[2][64][33] @131072 | bias @147968
#define GBUF_OFF 131072
#define BIAS_OFF 147968
#define SMEM_BYTES 148096

// ws (bytes): flags[128]@0 | xcdslot[16]@1024 | ready[16][32]u32 @2048 |
// abuf @4096: [2][64 b][4 kq][32 j][2 kg][8 s] bf16  (256KB per buffer)
#define WS_ABUF 4096
#define ABUF_HALF 131072 /* shorts per buffer */

__device__ __forceinline__ unsigned f2bf(float f) {  // fp32 -> bf16 RNE
  unsigned u = __float_as_uint(f);
  return (u + 0x7FFFu + ((u >> 16) & 1u)) >> 16;
}
__device__ __forceinline__ float sigf(float x) { return 1.0f / (1.0f + __expf(-x)); }
__device__ __forceinline__ float tanhf_(float x) { return 1.0f - 2.0f / (__expf(2.0f * x) + 1.0f); }

// a(0) = (1-m(0))*x(0) into new layout; h(0)=0 from memset.
__global__ void prep_a0(const float* __restrict__ x, const float* __restrict__ tm,
                        unsigned short* __restrict__ abuf) {
  int i = blockIdx.x * blockDim.x + threadIdx.x;  // over B_*D_
  if (i >= B_ * D_) return;
  int unit = i & (D_ - 1), b = i >> 10;
  float m = tm[b * T_];
  float a = (1.0f - m) * x[(size_t)b * T_ * D_ + unit];
  const int kq = unit >> 9, c = (unit >> 3) & 63, j = c >> 1, kg = c & 1, s = unit & 7;
  abuf[(unsigned)((b * 4 + kq) * 512 + j * 16 + kg * 8 + s)] = (unsigned short)f2bf(a);
}

__global__ __launch_bounds__(NTHR, 1)
void lstm_persist(const float* __restrict__ xf,
                  const float* __restrict__ tm,
                  const float* __restrict__ Wx, const float* __restrict__ bxp,
                  const float* __restrict__ Wh, const float* __restrict__ bhp,
                  float* __restrict__ out,
                  unsigned short* __restrict__ abuf,
                  unsigned* __restrict__ flags,
                  unsigned* __restrict__ xcdslot,
                  unsigned* __restrict__ ready)
{
  extern __shared__ char smem[];
  float* gbuf     = (float*)(smem + GBUF_OFF);  // [2][64][33]
  float* bias_lds = (float*)(smem + BIAS_OFF);

  const int tid = threadIdx.x;
  const int bid = blockIdx.x;

  // ---- stage weights -> LDS: row r = [Wx grow | Wh grow], 4096B, swizzled ----
  for (int r = 0; r < NROW; ++r) {
    const int grow = (r >> 3) * H_ + bid * UPB + (r & 7);
    const unsigned swz = (unsigned)((r & 15) << 4);
    float2 v = ((const float2*)(Wx + (size_t)grow * D_))[tid];
    *(unsigned*)(smem + (((unsigned)(r * 4096 + tid * 4)) ^ swz)) =
        f2bf(v.x) | (f2bf(v.y) << 16);
    v = ((const float2*)(Wh + (size_t)grow * H_))[tid];
    *(unsigned*)(smem + (((unsigned)(r * 4096 + 2048 + tid * 4)) ^ swz)) =
        f2bf(v.x) | (f2bf(v.y) << 16);
  }
  if (tid < NROW) {
    const int grow = (tid >> 3) * H_ + bid * UPB + (tid & 7);
    bias_lds[tid] = bxp[grow] + bhp[grow];
  }

  // ---- real-XCD leader election (correct under ANY block->XCD mapping) ----
  __shared__ unsigned s_ldr;
  unsigned xcdreg;
  asm volatile("s_getreg_b32 %0, hwreg(HW_REG_XCC_ID)" : "=s"(xcdreg));
  const unsigned myxcd = xcdreg & 15u;
  if (tid == 0) {
    unsigned slot = __hip_atomic_fetch_add(xcdslot + myxcd, 1u,
                                           __ATOMIC_RELAXED, __HIP_MEMORY_SCOPE_AGENT);
    s_ldr = (slot == 0u) ? 1u : 0u;
  }

  const int lane = tid & 63;
  const int wid  = tid >> 6;   // 0..7
  const int mt   = wid >> 2;   // M-tile (32 batch rows)
  const int kq   = wid & 3;    // K-quarter of 2048
  const int l31  = lane & 31;
  const int kg   = lane >> 5;  // 0..1
  const int m0   = mt * 32;

  const unsigned nswz  = (unsigned)((l31 & 15) << 4);
  const unsigned wrow  = (unsigned)(l31 * 4096);
  const unsigned kbase = (unsigned)(kq * 1024 + kg * 16);  // byte offset in row
  const unsigned rbase = (unsigned)(((m0 + l31) * 4 + kq) * 512 + kg * 8);  // shorts

  const int cb = tid >> 3;  // cell: batch
  const int cu = tid & 7;   // cell: unit within block
  // producer store coords (fixed per block/thread)
  const int kqA = bid >> 6, jj = (bid & 63) >> 1, kgg = bid & 1;
  const unsigned pbase = (unsigned)(cb * 4 * 512 + jj * 16 + kgg * 8 + cu);

  float ccell = 0.0f, hv = 0.0f;
  unsigned cur = 0;
  __syncthreads();
  const bool leader = (s_ldr != 0u);

  for (int t = 0; t < T_; ++t) {
    const int nxt = (t + 1 < T_) ? (t + 1) : t;
    const unsigned tgt = (unsigned)(t + 1);

    // cell-phase operands for next blend (plain cached; read-only data)
    const float mv = tm[cb * T_ + nxt];
    const float xv = xf[((size_t)cb * T_ + nxt) * D_ + bid * UPB + cu];

    // ---- A-frags: 32 x 16B batched sc0 loads (L1-bypass, L2-cached) ----
    short8 areg[32];
    {
      const unsigned long long pA = (unsigned long long)(uintptr_t)
          (abuf + cur * ABUF_HALF + rbase);
#define LDA(J, OFFS) asm volatile( \
      "global_load_dwordx4 %0, %1, off offset:" OFFS " sc0" \
      : "=v"(areg[J]) : "v"(pA))
      LDA(0, "0");    LDA(1, "32");   LDA(2, "64");   LDA(3, "96");
      LDA(4, "128");  LDA(5, "160");  LDA(6, "192");  LDA(7, "224");
      LDA(8, "256");  LDA(9, "288");  LDA(10, "320"); LDA(11, "352");
      LDA(12, "384"); LDA(13, "416"); LDA(14, "448"); LDA(15, "480");
      LDA(16, "512"); LDA(17, "544"); LDA(18, "576"); LDA(19, "608");
      LDA(20, "640"); LDA(21, "672"); LDA(22, "704"); LDA(23, "736");
      LDA(24, "768"); LDA(25, "800"); LDA(26, "832"); LDA(27, "864");
      LDA(28, "896"); LDA(29, "928"); LDA(30, "960"); LDA(31, "992");
#undef LDA
      asm volatile("s_waitcnt vmcnt(0)" ::: "memory");
      __builtin_amdgcn_sched_barrier(0);
    }

    f32x16 acc = {0,0,0,0,0,0,0,0,0,0,0,0,0,0,0,0};
#pragma unroll
    for (int j = 0; j < 32; ++j) {
      short8 w = *(const short8*)(smem +
                  ((wrow + kbase + (unsigned)(j * 32)) ^ nswz));
      acc = __builtin_amdgcn_mfma_f32_32x32x16_bf16(areg[j], w, acc, 0, 0, 0);
    }

    // ---- cross-kq reduce (gbuf in LDS) ----
    // C layout (32x32): col = lane&31, row = (e&3) + 8*(e>>2) + 4*(lane>>5)
    const int s = kq >> 1;
    if ((kq & 1) == 0) {
#pragma unroll
      for (int e = 0; e < 16; ++e) {
        const int br = m0 + (e & 3) + 8 * (e >> 2) + 4 * kg;
        float g = acc[e];
        if (kq == 0) g += bias_lds[l31];
        gbuf[(s * 64 + br) * 33 + l31] = g;
      }
    }
    __syncthreads();  // (B)
    if (kq & 1) {
#pragma unroll
      for (int e = 0; e < 16; ++e) {
        const int br = m0 + (e & 3) + 8 * (e >> 2) + 4 * kg;
        gbuf[(s * 64 + br) * 33 + l31] += acc[e];
      }
    }
    __syncthreads();  // (C)

    // ---- cell: one (b,u) per thread; ALL global stores agent write-through ----
    {
      const float* g0 = gbuf + cb * 33;
      const float* g1 = gbuf + (64 + cb) * 33;
      const float gi = g0[cu]      + g1[cu];
      const float gf = g0[8 + cu]  + g1[8 + cu];
      const float gg = g0[16 + cu] + g1[16 + cu];
      const float go = g0[24 + cu] + g1[24 + cu];
      const float iv = sigf(gi), fv = sigf(gf), gv = tanhf_(gg), ov = sigf(go);
      ccell = ccell * fv + iv * gv;
      hv = ov * tanhf_(ccell);

      const float av = mv * hv + (1.0f - mv) * xv;  // a(t+1) for this unit
      unsigned short* dst = abuf + (cur ^ 1u) * ABUF_HALF;
      __hip_atomic_store(dst + pbase + (unsigned)(kqA * 512),
                         (unsigned short)f2bf(av),
                         __ATOMIC_RELAXED, __HIP_MEMORY_SCOPE_AGENT);
      __hip_atomic_store(dst + pbase + (unsigned)((kqA + 2) * 512),
                         (unsigned short)f2bf(hv),
                         __ATOMIC_RELAXED, __HIP_MEMORY_SCOPE_AGENT);
    }

    __syncthreads();  // (D) s_barrier drains vmcnt -> a/h stores at L3
    if (tid == 0)
      __hip_atomic_store(flags + bid, tgt,
                         __ATOMIC_RELAXED, __HIP_MEMORY_SCOPE_AGENT);
    // out store off the protocol path (agent write-through: keeps L2 clean)
    __hip_atomic_store(out + ((size_t)cb * T_ + t) * H_ + bid * UPB + cu, hv,
                       __ATOMIC_RELAXED, __HIP_MEMORY_SCOPE_AGENT);

    if (leader) {
      if (wid == 0) {
        for (;;) {
          unsigned v0 = __hip_atomic_load(flags + lane,
                                          __ATOMIC_RELAXED, __HIP_MEMORY_SCOPE_AGENT);
          unsigned v1 = __hip_atomic_load(flags + 64 + lane,
                                          __ATOMIC_RELAXED, __HIP_MEMORY_SCOPE_AGENT);
          if (__all((v0 >= tgt) && (v1 >= tgt))) break;
          __builtin_amdgcn_s_sleep(1);
        }
        // L2 invalidate (nothing dirty anywhere by construction), then release
        __builtin_amdgcn_fence(__ATOMIC_ACQUIRE, "agent");
        asm volatile("s_waitcnt vmcnt(0)" ::: "memory");
        __builtin_amdgcn_sched_barrier(0);
        if (lane == 0)
          __hip_atomic_store(ready + myxcd * 32, tgt,
                             __ATOMIC_RELAXED, __HIP_MEMORY_SCOPE_AGENT);
      }
    } else {
      if (wid == 0) {
        while (__hip_atomic_load(ready + myxcd * 32,
                                 __ATOMIC_RELAXED, __HIP_MEMORY_SCOPE_AGENT) < tgt)
          __builtin_amdgcn_s_sleep(1);
      }
    }
    __syncthreads();  // (E)
    __builtin_amdgcn_sched_barrier(0);  // no A-load hoisting above the wait

    cur ^= 1u;
  }

  // finals: hn, cn
  out[(size_t)B_ * T_ * H_ + (size_t)cb * H_ + bid * UPB + cu] = hv;
  out[(size_t)B_ * T_ * H_ + (size_t)B_ * H_ + (size_t)cb * H_ + bid * UPB + cu] = ccell;
}

extern "C" void kernel_launch(void* const* d_in, const int* in_sizes, int n_in,
                              void* d_out, int out_size, void* d_ws, size_t ws_size,
                              hipStream_t stream) {
  const float* x  = (const float*)d_in[0];
  const float* tm = (const float*)d_in[1];
  const float* Wx = (const float*)d_in[2];
  const float* bx = (const float*)d_in[3];
  const float* Wh = (const float*)d_in[4];
  const float* bh = (const float*)d_in[5];
  float* out = (float*)d_out;
  char* ws = (char*)d_ws;

  unsigned* flags      = (unsigned*)ws;
  unsigned* xcdslot    = (unsigned*)(ws + 1024);
  unsigned* ready      = (unsigned*)(ws + 2048);
  unsigned short* abuf = (unsigned short*)(ws + WS_ABUF);

  // zero flags + xcdslot + ready + both [a|h] buffers (h(0)=0 comes from this)
  hipMemsetAsync(ws, 0, WS_ABUF + 2 * ABUF_HALF * 2, stream);
  prep_a0<<<dim3((B_ * D_ + 255) / 256), dim3(256), 0, stream>>>(x, tm, abuf);
  lstm_persist<<<dim3(NBLK), dim3(NTHR), SMEM_BYTES, stream>>>(
      x, tm, Wx, bx, Wh, bh, out, abuf, flags, xcdslot, ready);
}

// Round 7
// 5115.771 us; speedup vs baseline: 1.2947x; 1.2947x over previous
//
#include <hip/hip_runtime.h>
#include <stdint.h>

// Teacher-forced LSTM, B=64 T=512 D=H=1024.
// a(t) = m(t)*h(t-1) + (1-m(t))*x(t)   (computed in prev step's cell phase)
// gates(t) = [a(t) | h(t-1)] @ [Wx | Wh]^T + bias   -- one K=2048 GEMM
// Persistent: 256 blocks (all CUs) x 512 thr; block = (8 units x 32 batches)
//   -> 32 gate rows, 32-batch M-tile, 8 waves = 8 K-eighths (256 each).
// Weights bf16 [32 rows][4096B] LDS-stationary, 16-slot XOR swizzle.
// A-panel exchange: abuf[2][b][k] bf16 in ws; producers store agent-scope
// write-through (__hip_atomic_store); consumers load via ONE monolithic asm
// block: 16x global_load_dwordx4 sc1 (L2-bypass, L3-served) into pinned
// v[64:127], one s_waitcnt, 16 MFMAs -- no spill possible, one L3 latency.
// Barrier: per-block flag + block-0 master publishes gen; no cache fences.

#define B_ 64
#define T_ 512
#define D_ 1024
#define H_ 1024
#define NBLK 256
#define UPB 8
#define NROW 32
#define NTHR 512

typedef __attribute__((ext_vector_type(8))) short short8;
typedef __attribute__((ext_vector_type(16))) float f32x16;

// LDS (bytes): W 32x4096 swizzled @0 | gbuf float[4][32][33] @131072 | bias @147968
#define GBUF_OFF 131072
#define BIAS_OFF 147968
#define SMEM_BYTES 148096

// ws (bytes): flags[256] u32 @0 | gen u32 @2048 | abuf @4096: [2][64 b][2048 k] bf16
#define WS_ABUF 4096
#define ABUF_HALF (64 * 2048) /* shorts per buffer (256KB) */

__device__ __forceinline__ unsigned f2bf(float f) {  // fp32 -> bf16 RNE
  unsigned u = __float_as_uint(f);
  return (u + 0x7FFFu + ((u >> 16) & 1u)) >> 16;
}
__device__ __forceinline__ float sigf(float x) { return 1.0f / (1.0f + __expf(-x)); }
__device__ __forceinline__ float tanhf_(float x) { return 1.0f - 2.0f / (__expf(2.0f * x) + 1.0f); }

// a(0) = (1-m(0))*x(0); h(0)=0 from memset.
__global__ void prep_a0(const float* __restrict__ x, const float* __restrict__ tm,
                        unsigned short* __restrict__ abuf) {
  int i = blockIdx.x * blockDim.x + threadIdx.x;  // over B_*D_
  if (i >= B_ * D_) return;
  int d = i & (D_ - 1), b = i >> 10;
  float m = tm[b * T_];
  float a = (1.0f - m) * x[(size_t)b * T_ * D_ + d];
  abuf[b * 2048 + d] = (unsigned short)f2bf(a);
}

__global__ __launch_bounds__(NTHR, 1)
void lstm_persist(const float* __restrict__ xf,
                  const float* __restrict__ tm,
                  const float* __restrict__ Wx, const float* __restrict__ bxp,
                  const float* __restrict__ Wh, const float* __restrict__ bhp,
                  float* __restrict__ out,
                  unsigned short* __restrict__ abuf,
                  unsigned* __restrict__ flags,
                  unsigned* __restrict__ gen)
{
  extern __shared__ char smem[];
  float* gbuf     = (float*)(smem + GBUF_OFF);  // [4][32][33]
  float* bias_lds = (float*)(smem + BIAS_OFF);

  const int tid = threadIdx.x;
  const int bid = blockIdx.x;
  const int ug  = bid >> 1;        // unit group: units ug*8..ug*8+7
  const int bh  = bid & 1;         // batch half: batches bh*32..bh*32+31

  // ---- stage weights -> LDS: row r = [Wx grow | Wh grow], 4096B, swizzled ----
  for (int r = 0; r < NROW; ++r) {
    const int grow = (r >> 3) * H_ + ug * UPB + (r & 7);  // gate g=r>>3, unit u=r&7
    const unsigned swz = (unsigned)((r & 15) << 4);
    float2 v = ((const float2*)(Wx + (size_t)grow * D_))[tid];
    *(unsigned*)(smem + (((unsigned)(r * 4096 + tid * 4)) ^ swz)) =
        f2bf(v.x) | (f2bf(v.y) << 16);
    v = ((const float2*)(Wh + (size_t)grow * H_))[tid];
    *(unsigned*)(smem + (((unsigned)(r * 4096 + 2048 + tid * 4)) ^ swz)) =
        f2bf(v.x) | (f2bf(v.y) << 16);
  }
  if (tid < NROW) {
    const int grow = (tid >> 3) * H_ + ug * UPB + (tid & 7);
    bias_lds[tid] = bxp[grow] + bhp[grow];
  }

  const int lane = tid & 63;
  const int wid  = tid >> 6;   // 0..7 = K-eighth (256 k each)
  const int ko   = wid;
  const int l31  = lane & 31;  // batch row within the 32-batch tile
  const int kg   = lane >> 5;  // 0..1 k-half of 16

  const unsigned nswz = (unsigned)((l31 & 15) << 4);
  const unsigned wrow = (unsigned)(l31 * 4096);
  const unsigned kofs = (unsigned)(ko * 512 + kg * 16);  // byte offset of k in row

  // per-lane A base (shorts): abuf[cur][b = bh*32+l31][k = ko*256 + kg*8]
  const unsigned short* aptr0 =
      abuf + (size_t)(bh * 32 + l31) * 2048 + (unsigned)(ko * 256 + kg * 8);
  const unsigned short* aptr1 = aptr0 + ABUF_HALF;

  const int act = (tid < 256);  // cell-phase thread
  const int cb2 = (tid >> 3) & 31;   // batch within tile
  const int cu  = tid & 7;           // unit within group
  const int b   = bh * 32 + cb2;     // global batch
  const int hu  = ug * UPB + cu;     // global hidden unit
  float ccell = 0.0f, hv = 0.0f;

  unsigned cur = 0;
  __syncthreads();

  for (int t = 0; t < T_; ++t) {
    const int nxt = (t + 1 < T_) ? (t + 1) : t;
    const unsigned tgt = (unsigned)(t + 1);

    // ---- B-frags from LDS (compiler places + waits before asm) ----
#define LDW(J) (*(const short8*)(smem + wrow + ((kofs + (unsigned)((J) * 32)) ^ nswz)))
    short8 w0 = LDW(0), w1 = LDW(1), w2 = LDW(2), w3 = LDW(3);
    short8 w4 = LDW(4), w5 = LDW(5), w6 = LDW(6), w7 = LDW(7);
    short8 w8 = LDW(8), w9 = LDW(9), w10 = LDW(10), w11 = LDW(11);
    short8 w12 = LDW(12), w13 = LDW(13), w14 = LDW(14), w15 = LDW(15);
#undef LDW

    const unsigned long long pA =
        (unsigned long long)(uintptr_t)(cur ? aptr1 : aptr0);

    f32x16 acc = {0,0,0,0,0,0,0,0,0,0,0,0,0,0,0,0};
    // ---- monolithic: 16 batched sc1 loads -> pinned v[64:127], one wait, 16 MFMAs ----
    asm volatile(
      "global_load_dwordx4 v[64:67],   %[pa], off sc1\n\t"
      "global_load_dwordx4 v[68:71],   %[pa], off offset:32 sc1\n\t"
      "global_load_dwordx4 v[72:75],   %[pa], off offset:64 sc1\n\t"
      "global_load_dwordx4 v[76:79],   %[pa], off offset:96 sc1\n\t"
      "global_load_dwordx4 v[80:83],   %[pa], off offset:128 sc1\n\t"
      "global_load_dwordx4 v[84:87],   %[pa], off offset:160 sc1\n\t"
      "global_load_dwordx4 v[88:91],   %[pa], off offset:192 sc1\n\t"
      "global_load_dwordx4 v[92:95],   %[pa], off offset:224 sc1\n\t"
      "global_load_dwordx4 v[96:99],   %[pa], off offset:256 sc1\n\t"
      "global_load_dwordx4 v[100:103], %[pa], off offset:288 sc1\n\t"
      "global_load_dwordx4 v[104:107], %[pa], off offset:320 sc1\n\t"
      "global_load_dwordx4 v[108:111], %[pa], off offset:352 sc1\n\t"
      "global_load_dwordx4 v[112:115], %[pa], off offset:384 sc1\n\t"
      "global_load_dwordx4 v[116:119], %[pa], off offset:416 sc1\n\t"
      "global_load_dwordx4 v[120:123], %[pa], off offset:448 sc1\n\t"
      "global_load_dwordx4 v[124:127], %[pa], off offset:480 sc1\n\t"
      "s_waitcnt vmcnt(0)\n\t"
      "v_mfma_f32_32x32x16_bf16 %[acc], v[64:67],   %[w0],  %[acc]\n\t"
      "v_mfma_f32_32x32x16_bf16 %[acc], v[68:71],   %[w1],  %[acc]\n\t"
      "v_mfma_f32_32x32x16_bf16 %[acc], v[72:75],   %[w2],  %[acc]\n\t"
      "v_mfma_f32_32x32x16_bf16 %[acc], v[76:79],   %[w3],  %[acc]\n\t"
      "v_mfma_f32_32x32x16_bf16 %[acc], v[80:83],   %[w4],  %[acc]\n\t"
      "v_mfma_f32_32x32x16_bf16 %[acc], v[84:87],   %[w5],  %[acc]\n\t"
      "v_mfma_f32_32x32x16_bf16 %[acc], v[88:91],   %[w6],  %[acc]\n\t"
      "v_mfma_f32_32x32x16_bf16 %[acc], v[92:95],   %[w7],  %[acc]\n\t"
      "v_mfma_f32_32x32x16_bf16 %[acc], v[96:99],   %[w8],  %[acc]\n\t"
      "v_mfma_f32_32x32x16_bf16 %[acc], v[100:103], %[w9],  %[acc]\n\t"
      "v_mfma_f32_32x32x16_bf16 %[acc], v[104:107], %[w10], %[acc]\n\t"
      "v_mfma_f32_32x32x16_bf16 %[acc], v[108:111], %[w11], %[acc]\n\t"
      "v_mfma_f32_32x32x16_bf16 %[acc], v[112:115], %[w12], %[acc]\n\t"
      "v_mfma_f32_32x32x16_bf16 %[acc], v[116:119], %[w13], %[acc]\n\t"
      "v_mfma_f32_32x32x16_bf16 %[acc], v[120:123], %[w14], %[acc]\n\t"
      "v_mfma_f32_32x32x16_bf16 %[acc], v[124:127], %[w15], %[acc]"
      : [acc] "+v"(acc)
      : [pa] "v"(pA),
        [w0] "v"(w0), [w1] "v"(w1), [w2] "v"(w2), [w3] "v"(w3),
        [w4] "v"(w4), [w5] "v"(w5), [w6] "v"(w6), [w7] "v"(w7),
        [w8] "v"(w8), [w9] "v"(w9), [w10] "v"(w10), [w11] "v"(w11),
        [w12] "v"(w12), [w13] "v"(w13), [w14] "v"(w14), [w15] "v"(w15)
      : "memory",
        "v64","v65","v66","v67","v68","v69","v70","v71",
        "v72","v73","v74","v75","v76","v77","v78","v79",
        "v80","v81","v82","v83","v84","v85","v86","v87",
        "v88","v89","v90","v91","v92","v93","v94","v95",
        "v96","v97","v98","v99","v100","v101","v102","v103",
        "v104","v105","v106","v107","v108","v109","v110","v111",
        "v112","v113","v114","v115","v116","v117","v118","v119",
        "v120","v121","v122","v123","v124","v125","v126","v127");

    // ---- cell operands for t+1 (issued after asm; overlap epilogue) ----
    float mv = 0.0f, xv = 0.0f;
    if (act) {
      mv = tm[b * T_ + nxt];
      xv = xf[((size_t)b * T_ + nxt) * D_ + hu];
    }

    // ---- cross-wave reduce into 4 slabs ----
    // C layout (32x32): col = lane&31 (gate row), row = (e&3)+8*(e>>2)+4*kg (batch)
    {
      float* slab = gbuf + (wid & 3) * (32 * 33);
      if (wid < 4) {
#pragma unroll
        for (int e = 0; e < 16; ++e) {
          const int br = (e & 3) + 8 * (e >> 2) + 4 * kg;
          slab[br * 33 + l31] = acc[e];
        }
      }
      __syncthreads();  // (B)
      if (wid >= 4) {
#pragma unroll
        for (int e = 0; e < 16; ++e) {
          const int br = (e & 3) + 8 * (e >> 2) + 4 * kg;
          slab[br * 33 + l31] += acc[e];
        }
      }
      __syncthreads();  // (C)
    }

    // ---- cell: one (b,u) per thread (tid<256) ----
    if (act) {
      float gi = bias_lds[cu],      gf = bias_lds[8 + cu];
      float gg = bias_lds[16 + cu], go = bias_lds[24 + cu];
#pragma unroll
      for (int s = 0; s < 4; ++s) {
        const float* row = gbuf + s * (32 * 33) + cb2 * 33;
        gi += row[cu];      gf += row[8 + cu];
        gg += row[16 + cu]; go += row[24 + cu];
      }
      const float iv = sigf(gi), fv = sigf(gf), gv = tanhf_(gg), ov = sigf(go);
      ccell = ccell * fv + iv * gv;
      hv = ov * tanhf_(ccell);

      const float av = mv * hv + (1.0f - mv) * xv;  // a(t+1) for (b, hu)
      unsigned short* dst = abuf + (cur ^ 1u) * ABUF_HALF + b * 2048;
      __hip_atomic_store(dst + hu, (unsigned short)f2bf(av),
                         __ATOMIC_RELAXED, __HIP_MEMORY_SCOPE_AGENT);
      __hip_atomic_store(dst + 1024 + hu, (unsigned short)f2bf(hv),
                         __ATOMIC_RELAXED, __HIP_MEMORY_SCOPE_AGENT);
    }

    __syncthreads();  // (D) drains a/h stores (vmcnt(0) before s_barrier)

    if (bid == 0) {
      if (act) out[((size_t)b * T_ + t) * H_ + hu] = hv;  // off critical path
      if (wid == 0) {
        for (;;) {
          unsigned v0 = (lane == 0) ? tgt
              : __hip_atomic_load(flags + lane, __ATOMIC_RELAXED, __HIP_MEMORY_SCOPE_AGENT);
          unsigned v1 = __hip_atomic_load(flags + 64 + lane,
                                          __ATOMIC_RELAXED, __HIP_MEMORY_SCOPE_AGENT);
          unsigned v2 = __hip_atomic_load(flags + 128 + lane,
                                          __ATOMIC_RELAXED, __HIP_MEMORY_SCOPE_AGENT);
          unsigned v3 = __hip_atomic_load(flags + 192 + lane,
                                          __ATOMIC_RELAXED, __HIP_MEMORY_SCOPE_AGENT);
          if (__all((v0 >= tgt) && (v1 >= tgt) && (v2 >= tgt) && (v3 >= tgt))) break;
          __builtin_amdgcn_s_sleep(1);
        }
        if (lane == 0)
          __hip_atomic_store(gen, tgt, __ATOMIC_RELAXED, __HIP_MEMORY_SCOPE_AGENT);
      }
    } else {
      if (tid == 0)
        __hip_atomic_store(flags + bid, tgt,
                           __ATOMIC_RELAXED, __HIP_MEMORY_SCOPE_AGENT);
      if (act) out[((size_t)b * T_ + t) * H_ + hu] = hv;  // overlaps gen wait
      if (wid == 0) {
        while (__hip_atomic_load(gen, __ATOMIC_RELAXED, __HIP_MEMORY_SCOPE_AGENT) < tgt)
          __builtin_amdgcn_s_sleep(1);
      }
    }
    __syncthreads();  // (E)
    __builtin_amdgcn_sched_barrier(0);  // nothing hoists above the wait

    cur ^= 1u;
  }

  // finals: hn, cn
  if (act) {
    out[(size_t)B_ * T_ * H_ + (size_t)b * H_ + hu] = hv;
    out[(size_t)B_ * T_ * H_ + (size_t)B_ * H_ + (size_t)b * H_ + hu] = ccell;
  }
}

extern "C" void kernel_launch(void* const* d_in, const int* in_sizes, int n_in,
                              void* d_out, int out_size, void* d_ws, size_t ws_size,
                              hipStream_t stream) {
  const float* x  = (const float*)d_in[0];
  const float* tm = (const float*)d_in[1];
  const float* Wx = (const float*)d_in[2];
  const float* bx = (const float*)d_in[3];
  const float* Wh = (const float*)d_in[4];
  const float* bh = (const float*)d_in[5];
  float* out = (float*)d_out;
  char* ws = (char*)d_ws;

  unsigned* flags      = (unsigned*)ws;
  unsigned* gen        = (unsigned*)(ws + 2048);
  unsigned short* abuf = (unsigned short*)(ws + WS_ABUF);

  // zero flags + gen + both [a|h] buffers (h(0)=0 comes from this)
  hipMemsetAsync(ws, 0, WS_ABUF + 2 * ABUF_HALF * 2, stream);
  prep_a0<<<dim3((B_ * D_ + 255) / 256), dim3(256), 0, stream>>>(x, tm, abuf);
  lstm_persist<<<dim3(NBLK), dim3(NTHR), SMEM_BYTES, stream>>>(
      x, tm, Wx, bx, Wh, bh, out, abuf, flags, gen);
}